// Round 1
// baseline (314.636 us; speedup 1.0000x reference)
//
#include <hip/hip_runtime.h>
#include <hip/hip_cooperative_groups.h>

namespace cg = cooperative_groups;

#define H 64
#define NPB 64
#define KS 104      // bf16 elems per A-row: 64 data + xv + sv + zero-pad; 208B = 13x16B
typedef short bf16x8 __attribute__((ext_vector_type(8)));
typedef float f32x4 __attribute__((ext_vector_type(4)));

static __device__ __forceinline__ unsigned short f2bf(float f) {
    union { float f; unsigned u; } v; v.f = f;
    unsigned r = v.u + 0x7fffu + ((v.u >> 16) & 1u);
    return (unsigned short)(r >> 16);
}
static __device__ __forceinline__ float bf2f(unsigned short b) {
    union { unsigned u; float f; } v; v.u = ((unsigned)b) << 16;
    return v.f;
}
static __device__ __forceinline__ void split8(const float* ff, bf16x8& hi, bf16x8& lo) {
#pragma unroll
    for (int j = 0; j < 8; ++j) {
        unsigned short h = f2bf(ff[j]);
        hi[j] = (short)h;
        lo[j] = (short)f2bf(ff[j] - bf2f(h));
    }
}
// device-visible 16B store (atomicExch executes at the device coherence point,
// so later first-touch plain loads from any XCD see it without a kernel boundary)
static __device__ __forceinline__ void store16_dev(bf16x8* dst, bf16x8 v) {
    union { bf16x8 v; unsigned long long u[2]; } cv; cv.v = v;
    unsigned long long* p = (unsigned long long*)dst;
    atomicExch(p, cv.u[0]);
    atomicExch(p + 1, cv.u[1]);
}

// ws layout (bytes): dS [N*8] | gp [256] | Bpre [196608] | W7pre [32768]
// Bpre frag index: ((tl*4+w)*3+s)*128 + hilo*64 + lane   (each entry = 8 bf16)
// W7pre frag index: (w*2+s)*128 + hilo*64 + lane

// ===========================================================================
// FUSED cooperative kernel: prep -> sync -> edges -> sync -> nodes -> sync -> finalize
// ===========================================================================
__global__ __launch_bounds__(256, 2)
void fused_kernel(const float* __restrict__ mu, const float* __restrict__ x,
                  const int* __restrict__ ei, const float* __restrict__ ew,
                  const float* __restrict__ W1, const float* __restrict__ W2,
                  const float* __restrict__ W3, const float* __restrict__ W4,
                  const float* __restrict__ W5, const float* __restrict__ W7,
                  double* __restrict__ dS, float* __restrict__ gp,
                  bf16x8* __restrict__ Bp, bf16x8* __restrict__ W7p,
                  float* __restrict__ out, int N, int E, int nT) {
    __shared__ unsigned short Ab[2][NPB * KS];
    __shared__ float degs[NPB];
    __shared__ float red[4 * NPB];
    __shared__ float v3s[H];

    const int t = threadIdx.x;
    const int bid = blockIdx.x;
    const int gsz = gridDim.x;
    const int lane = t & 63;
    const int w = __builtin_amdgcn_readfirstlane(t >> 6);
    const int c = lane & 15;
    const int q = lane >> 4;
    const int hh = 16 * w + c;

    // ---- Phase 0: zero dS+gp (device-visible) + build weight fragments -----
    {
        unsigned long long* z = (unsigned long long*)dS;  // gp is contiguous after dS
        const int tot = N + 32;                           // N doubles + 64 floats
        for (int i = bid * 256 + t; i < tot; i += gsz * 256) atomicExch(z + i, 0ULL);
    }
    if (bid < 16) {           // block (tl, wl): Bp fragments
        const int tl = bid >> 2, wl = bid & 3;
        if (t < H) {          // v3[h] = sum_k relu(W4[tl][k]) * W3[tl][h][k]
            const float* __restrict__ w3r = W3 + (tl * H + t) * H;
            const float* __restrict__ w4r = W4 + tl * H;
            float a0 = 0, a1 = 0, a2 = 0, a3 = 0;
#pragma unroll
            for (int k = 0; k < H; k += 4) {
                a0 += fmaxf(w4r[k + 0], 0.f) * w3r[k + 0];
                a1 += fmaxf(w4r[k + 1], 0.f) * w3r[k + 1];
                a2 += fmaxf(w4r[k + 2], 0.f) * w3r[k + 2];
                a3 += fmaxf(w4r[k + 3], 0.f) * w3r[k + 3];
            }
            v3s[t] = (a0 + a1) + (a2 + a3);
        }
        __syncthreads();
        if (t < 64) {
            const int cc = t & 15, qq = t >> 4, hw = 16 * wl + cc;
            const int b3 = (tl * 4 + wl) * 3;
            bf16x8 hi, lo;
#pragma unroll
            for (int s = 0; s < 2; ++s) {
                const float* __restrict__ wp = W2 + (tl * H + hw) * H + s * 32 + qq * 8;
                float4 f0 = *(const float4*)(wp);
                float4 f1 = *(const float4*)(wp + 4);
                float ff[8] = {f0.x, f0.y, f0.z, f0.w, f1.x, f1.y, f1.z, f1.w};
                split8(ff, hi, lo);
                store16_dev(&Bp[(b3 + s) * 128 + t], hi);
                store16_dev(&Bp[(b3 + s) * 128 + 64 + t], lo);
            }
            float ff[8] = {0, 0, 0, 0, 0, 0, 0, 0};
            if (qq == 0) { ff[0] = W1[tl * H + hw]; ff[1] = v3s[hw]; }
            split8(ff, hi, lo);
            store16_dev(&Bp[(b3 + 2) * 128 + t], hi);
            store16_dev(&Bp[(b3 + 2) * 128 + 64 + t], lo);
        }
    } else if (bid < 20) {    // block (16+wl): W7p fragments
        const int wl = bid - 16;
        if (t < 64) {
            const int cc = t & 15, qq = t >> 4, hw = 16 * wl + cc;
            bf16x8 hi, lo;
#pragma unroll
            for (int s = 0; s < 2; ++s) {
                const float* __restrict__ wp = W7 + hw * H + s * 32 + qq * 8;
                float4 f0 = *(const float4*)(wp);
                float4 f1 = *(const float4*)(wp + 4);
                float ff[8] = {f0.x, f0.y, f0.z, f0.w, f1.x, f1.y, f1.z, f1.w};
                split8(ff, hi, lo);
                store16_dev(&W7p[(wl * 2 + s) * 128 + t], hi);
                store16_dev(&W7p[(wl * 2 + s) * 128 + 64 + t], lo);
            }
        }
    }
    __threadfence();
    cg::this_grid().sync();

    // ---- Phase 1: edge accumulation (one fp64 atomic packs deg & S) --------
    {
        int probe = ei[2 * (t & 63) + 1];
        bool is64 = (__ballot(probe != 0) == 0ULL);       // wave-uniform
        const int nq = (E + 3) >> 2;
        for (int qd = bid * 256 + t; qd < nq; qd += gsz * 256) {
            int e0 = 4 * qd;
            if (e0 + 3 < E) {
                float4 wv = *(const float4*)(ew + e0);
                int i0, i1, i2, i3;
                if (is64) {
                    int4 a = *(const int4*)(ei + 2 * (E + e0));
                    int4 b = *(const int4*)(ei + 2 * (E + e0) + 4);
                    i0 = a.x; i1 = a.z; i2 = b.x; i3 = b.z;
                } else {
                    int4 a = *(const int4*)(ei + E + e0);
                    i0 = a.x; i1 = a.y; i2 = a.z; i3 = a.w;
                }
                unsafeAtomicAdd(&dS[i0], 4096.0 + (double)wv.x);
                unsafeAtomicAdd(&dS[i1], 4096.0 + (double)wv.y);
                unsafeAtomicAdd(&dS[i2], 4096.0 + (double)wv.z);
                unsafeAtomicAdd(&dS[i3], 4096.0 + (double)wv.w);
            } else {
                for (int j = 0; j < 4 && e0 + j < E; ++j) {
                    int e = e0 + j;
                    int idx = is64 ? ei[2 * (E + e)] : ei[E + e];
                    unsafeAtomicAdd(&dS[idx], 4096.0 + (double)ew[e]);
                }
            }
        }
    }
    __threadfence();
    cg::this_grid().sync();

    // ---- Phase 2: node tiles (grid-stride), pn kept in registers -----------
    // zero pad cols 66..103 once (never overwritten by stage/epilogue)
    if (t < 128) {
        int buf = t >> 6, row = t & 63;
        unsigned* p = (unsigned*)&Ab[buf][row * KS];
#pragma unroll
        for (int d = 33; d < 52; ++d) p[d] = 0u;
    }
    float pn_s[4] = {0.f, 0.f, 0.f, 0.f};
#pragma unroll
    for (int it = 0; it < 4; ++it) {
        const int tile = bid + it * gsz;
        if (tile >= nT) break;                     // block-uniform
        const int base = tile * NPB;

        // per-node scalars; xv/sv -> cols 64/65 of BOTH buffers
        if (t < 64) {
            int node = base + t;
            float dg = 0.f, sv = 0.f, xv = 0.f;
            if (node < N) {
                double T = dS[node];
                double k = floor(T * (1.0 / 4096.0));
                dg = (float)k;
                sv = (float)(T - 4096.0 * k);
                xv = x[node];
            }
            degs[t] = dg;
            unsigned short xb = f2bf(xv), sb = f2bf(sv);
            Ab[0][t * KS + 64] = xb; Ab[0][t * KS + 65] = sb;
            Ab[1][t * KS + 64] = xb; Ab[1][t * KS + 65] = sb;
        }
        __syncthreads();

        // stage A0 = deg[m] * mu (bf16), coalesced
        {
            const float* __restrict__ mublk = mu + (size_t)base * H;
            const int maxf = (N - base) * H;
#pragma unroll
            for (int cc = 0; cc < 4; ++cc) {
                int f = (t + 256 * cc) * 4;
                float4 v = make_float4(0.f, 0.f, 0.f, 0.f);
                if (f < maxf) v = *(const float4*)(mublk + f);
                int m = f >> 6, k = f & 63;
                float dg = degs[m];
                ushort4 b;
                b.x = f2bf(v.x * dg); b.y = f2bf(v.y * dg);
                b.z = f2bf(v.z * dg); b.w = f2bf(v.w * dg);
                *(ushort4*)(&Ab[0][m * KS + k]) = b;
            }
        }
        __syncthreads();

        unsigned short* Acur = &Ab[0][0];
        unsigned short* Anxt = &Ab[1][0];

        for (int tl = 0; tl < 4; ++tl) {
            const int b3 = (tl * 4 + w) * 3;
            bf16x8 bh0 = Bp[(b3 + 0) * 128 + lane], bl0 = Bp[(b3 + 0) * 128 + 64 + lane];
            bf16x8 bh1 = Bp[(b3 + 1) * 128 + lane], bl1 = Bp[(b3 + 1) * 128 + 64 + lane];
            bf16x8 bh2 = Bp[(b3 + 2) * 128 + lane], bl2 = Bp[(b3 + 2) * 128 + 64 + lane];

            f32x4 acc[4];
#pragma unroll
            for (int mt = 0; mt < 4; ++mt)
#pragma unroll
                for (int r = 0; r < 4; ++r) acc[mt][r] = 0.f;

#pragma unroll
            for (int mt = 0; mt < 4; ++mt) {
                const unsigned short* ar = Acur + (mt * 16 + c) * KS;
                bf16x8 a0 = *(const bf16x8*)(ar + q * 8);
                bf16x8 a1 = *(const bf16x8*)(ar + 32 + q * 8);
                bf16x8 a2 = *(const bf16x8*)(ar + 64 + q * 8);
                acc[mt] = __builtin_amdgcn_mfma_f32_16x16x32_bf16(a0, bh0, acc[mt], 0, 0, 0);
                acc[mt] = __builtin_amdgcn_mfma_f32_16x16x32_bf16(a0, bl0, acc[mt], 0, 0, 0);
                acc[mt] = __builtin_amdgcn_mfma_f32_16x16x32_bf16(a1, bh1, acc[mt], 0, 0, 0);
                acc[mt] = __builtin_amdgcn_mfma_f32_16x16x32_bf16(a1, bl1, acc[mt], 0, 0, 0);
                acc[mt] = __builtin_amdgcn_mfma_f32_16x16x32_bf16(a2, bh2, acc[mt], 0, 0, 0);
                acc[mt] = __builtin_amdgcn_mfma_f32_16x16x32_bf16(a2, bl2, acc[mt], 0, 0, 0);
            }

            const bool scale = (tl < 3);
#pragma unroll
            for (int mt = 0; mt < 4; ++mt) {
#pragma unroll
                for (int r = 0; r < 4; ++r) {
                    int m = mt * 16 + q * 4 + r;
                    float v = fmaxf(acc[mt][r], 0.f);
                    if (scale) v *= degs[m];
                    Anxt[m * KS + hh] = f2bf(v);
                }
            }
            __syncthreads();
            unsigned short* tmp = Acur; Acur = Anxt; Anxt = tmp;
        }

        // W7 matmul + per-node term: pn[m] = sum_h relu(mu.W7[h,:]) * W5[64+h]
        {
            bf16x8 bh0 = W7p[(w * 2 + 0) * 128 + lane], bl0 = W7p[(w * 2 + 0) * 128 + 64 + lane];
            bf16x8 bh1 = W7p[(w * 2 + 1) * 128 + lane], bl1 = W7p[(w * 2 + 1) * 128 + 64 + lane];
            f32x4 acc[4];
#pragma unroll
            for (int mt = 0; mt < 4; ++mt)
#pragma unroll
                for (int r = 0; r < 4; ++r) acc[mt][r] = 0.f;
#pragma unroll
            for (int mt = 0; mt < 4; ++mt) {
                const unsigned short* ar = Acur + (mt * 16 + c) * KS;
                bf16x8 a0 = *(const bf16x8*)(ar + q * 8);
                bf16x8 a1 = *(const bf16x8*)(ar + 32 + q * 8);
                acc[mt] = __builtin_amdgcn_mfma_f32_16x16x32_bf16(a0, bh0, acc[mt], 0, 0, 0);
                acc[mt] = __builtin_amdgcn_mfma_f32_16x16x32_bf16(a0, bl0, acc[mt], 0, 0, 0);
                acc[mt] = __builtin_amdgcn_mfma_f32_16x16x32_bf16(a1, bh1, acc[mt], 0, 0, 0);
                acc[mt] = __builtin_amdgcn_mfma_f32_16x16x32_bf16(a1, bl1, acc[mt], 0, 0, 0);
            }
            float w5v = W5[H + hh];
#pragma unroll
            for (int mt = 0; mt < 4; ++mt) {
#pragma unroll
                for (int r = 0; r < 4; ++r) {
                    float v = fmaxf(acc[mt][r], 0.f) * w5v;
                    v += __shfl_xor(v, 1);
                    v += __shfl_xor(v, 2);
                    v += __shfl_xor(v, 4);
                    v += __shfl_xor(v, 8);
                    if (c == 0) red[w * 64 + mt * 16 + q * 4 + r] = v;
                }
            }
        }
        __syncthreads();
        if (t < 64) pn_s[it] = red[t] + red[64 + t] + red[128 + t] + red[192 + t];
        __syncthreads();

        // graph pool partials from final mu
        {
            int h = t & 63, mq = t >> 6;
            float s = 0.f;
#pragma unroll
            for (int i = 0; i < 16; ++i) s += bf2f(Acur[(mq * 16 + i) * KS + h]);
            red[t] = s;
        }
        __syncthreads();
        if (t < 64) {
            float g = red[t] + red[64 + t] + red[128 + t] + red[192 + t];
            unsafeAtomicAdd(&gp[t], g);
        }
    }
    __threadfence();
    cg::this_grid().sync();

    // ---- Phase 3: C = sum_h relu(gp[h])*W5[h]; out = pn + C ----------------
    float C;
    {
        float v = fmaxf(gp[lane], 0.f) * W5[lane];
        v += __shfl_xor(v, 1);
        v += __shfl_xor(v, 2);
        v += __shfl_xor(v, 4);
        v += __shfl_xor(v, 8);
        v += __shfl_xor(v, 16);
        v += __shfl_xor(v, 32);
        C = v;
    }
    if (t < 64) {
#pragma unroll
        for (int it = 0; it < 4; ++it) {
            const int tile = bid + it * gsz;
            if (tile >= nT) break;
            const int node = tile * NPB + t;
            if (node < N) out[node] = pn_s[it] + C;
        }
    }
}

// ===========================================================================
// Fallback path: the previously-verified 4-kernel chain (unchanged).
// ===========================================================================
__global__ __launch_bounds__(256)
void prep_kernel(const float* __restrict__ W1, const float* __restrict__ W2,
                 const float* __restrict__ W3, const float* __restrict__ W4,
                 const float* __restrict__ W7, unsigned* __restrict__ zero_base,
                 int zero_dwords, bf16x8* __restrict__ Bp, bf16x8* __restrict__ W7p) {
    const int t = threadIdx.x;
    if (blockIdx.x != 0) {
        int idx = (blockIdx.x - 1) * 256 + t;
        for (int i = idx; i < zero_dwords; i += 64 * 256) zero_base[i] = 0u;
        return;
    }
    __shared__ float v3s[4 * H];
    {
        int tl = t >> 6, h = t & 63;
        const float* __restrict__ w3r = W3 + (tl * H + h) * H;
        const float* __restrict__ w4r = W4 + tl * H;
        float a0 = 0, a1 = 0, a2 = 0, a3 = 0;
#pragma unroll
        for (int k = 0; k < H; k += 4) {
            a0 += fmaxf(w4r[k + 0], 0.f) * w3r[k + 0];
            a1 += fmaxf(w4r[k + 1], 0.f) * w3r[k + 1];
            a2 += fmaxf(w4r[k + 2], 0.f) * w3r[k + 2];
            a3 += fmaxf(w4r[k + 3], 0.f) * w3r[k + 3];
        }
        v3s[t] = (a0 + a1) + (a2 + a3);
    }
    __syncthreads();
    const int w = t >> 6, lane = t & 63, c = lane & 15, q = lane >> 4;
    const int hh = 16 * w + c;
    for (int tl = 0; tl < 4; ++tl) {
        const int b3 = (tl * 4 + w) * 3;
        bf16x8 hi, lo;
#pragma unroll
        for (int s = 0; s < 2; ++s) {
            const float* __restrict__ wp = W2 + (tl * H + hh) * H + s * 32 + q * 8;
            float4 f0 = *(const float4*)(wp);
            float4 f1 = *(const float4*)(wp + 4);
            float ff[8] = {f0.x, f0.y, f0.z, f0.w, f1.x, f1.y, f1.z, f1.w};
            split8(ff, hi, lo);
            Bp[(b3 + s) * 128 + lane] = hi;
            Bp[(b3 + s) * 128 + 64 + lane] = lo;
        }
        float ff[8] = {0, 0, 0, 0, 0, 0, 0, 0};
        if (q == 0) { ff[0] = W1[tl * H + hh]; ff[1] = v3s[tl * H + hh]; }
        split8(ff, hi, lo);
        Bp[(b3 + 2) * 128 + lane] = hi;
        Bp[(b3 + 2) * 128 + 64 + lane] = lo;
    }
#pragma unroll
    for (int s = 0; s < 2; ++s) {
        const float* __restrict__ wp = W7 + hh * H + s * 32 + q * 8;
        float4 f0 = *(const float4*)(wp);
        float4 f1 = *(const float4*)(wp + 4);
        float ff[8] = {f0.x, f0.y, f0.z, f0.w, f1.x, f1.y, f1.z, f1.w};
        bf16x8 hi, lo;
        split8(ff, hi, lo);
        W7p[(w * 2 + s) * 128 + lane] = hi;
        W7p[(w * 2 + s) * 128 + 64 + lane] = lo;
    }
}

__global__ __launch_bounds__(256)
void edge_kernel(const int* __restrict__ ei, const float* __restrict__ ew,
                 double* __restrict__ dS, int E) {
    int probe = ei[2 * (threadIdx.x & 63) + 1];
    bool is64 = (__ballot(probe != 0) == 0ULL);
    int e0 = 4 * (blockIdx.x * blockDim.x + threadIdx.x);
    if (e0 >= E) return;
    if (e0 + 3 < E) {
        float4 wv = *(const float4*)(ew + e0);
        int i0, i1, i2, i3;
        if (is64) {
            int4 a = *(const int4*)(ei + 2 * (E + e0));
            int4 b = *(const int4*)(ei + 2 * (E + e0) + 4);
            i0 = a.x; i1 = a.z; i2 = b.x; i3 = b.z;
        } else {
            int4 a = *(const int4*)(ei + E + e0);
            i0 = a.x; i1 = a.y; i2 = a.z; i3 = a.w;
        }
        unsafeAtomicAdd(&dS[i0], 4096.0 + (double)wv.x);
        unsafeAtomicAdd(&dS[i1], 4096.0 + (double)wv.y);
        unsafeAtomicAdd(&dS[i2], 4096.0 + (double)wv.z);
        unsafeAtomicAdd(&dS[i3], 4096.0 + (double)wv.w);
    } else {
        for (int j = 0; j < 4 && e0 + j < E; ++j) {
            int e = e0 + j;
            int idx = is64 ? ei[2 * (E + e)] : ei[E + e];
            unsafeAtomicAdd(&dS[idx], 4096.0 + (double)ew[e]);
        }
    }
}

__global__ __launch_bounds__(256, 2)
void node_kernel(const float* __restrict__ mu, const float* __restrict__ x,
                 const float* __restrict__ W5, const bf16x8* __restrict__ Bp,
                 const bf16x8* __restrict__ W7p, const double* __restrict__ dS,
                 float* __restrict__ gp, float* __restrict__ out, int N) {
    __shared__ unsigned short Ab[2][NPB * KS];
    __shared__ float degs[NPB];
    __shared__ float red[4 * NPB];

    const int t = threadIdx.x;
    const int lane = t & 63;
    const int w = __builtin_amdgcn_readfirstlane(t >> 6);
    const int c = lane & 15;
    const int q = lane >> 4;
    const int hh = 16 * w + c;
    const int base = blockIdx.x * NPB;

    if (t < 128) {
        int buf = t >> 6, row = t & 63;
        unsigned* p = (unsigned*)&Ab[buf][row * KS];
#pragma unroll
        for (int d = 33; d < 52; ++d) p[d] = 0u;
    }
    if (t < 64) {
        int node = base + t;
        float dg = 0.f, sv = 0.f, xv = 0.f;
        if (node < N) {
            double T = dS[node];
            double k = floor(T * (1.0 / 4096.0));
            dg = (float)k;
            sv = (float)(T - 4096.0 * k);
            xv = x[node];
        }
        degs[t] = dg;
        unsigned short xb = f2bf(xv), sb = f2bf(sv);
        Ab[0][t * KS + 64] = xb; Ab[0][t * KS + 65] = sb;
        Ab[1][t * KS + 64] = xb; Ab[1][t * KS + 65] = sb;
    }
    __syncthreads();

    {
        const float* __restrict__ mublk = mu + (size_t)base * H;
        const int maxf = (N - base) * H;
#pragma unroll
        for (int cc = 0; cc < 4; ++cc) {
            int f = (t + 256 * cc) * 4;
            float4 v = make_float4(0.f, 0.f, 0.f, 0.f);
            if (f < maxf) v = *(const float4*)(mublk + f);
            int m = f >> 6, k = f & 63;
            float dg = degs[m];
            ushort4 b;
            b.x = f2bf(v.x * dg); b.y = f2bf(v.y * dg);
            b.z = f2bf(v.z * dg); b.w = f2bf(v.w * dg);
            *(ushort4*)(&Ab[0][m * KS + k]) = b;
        }
    }
    __syncthreads();

    unsigned short* Acur = &Ab[0][0];
    unsigned short* Anxt = &Ab[1][0];

    for (int tl = 0; tl < 4; ++tl) {
        const int b3 = (tl * 4 + w) * 3;
        bf16x8 bh0 = Bp[(b3 + 0) * 128 + lane], bl0 = Bp[(b3 + 0) * 128 + 64 + lane];
        bf16x8 bh1 = Bp[(b3 + 1) * 128 + lane], bl1 = Bp[(b3 + 1) * 128 + 64 + lane];
        bf16x8 bh2 = Bp[(b3 + 2) * 128 + lane], bl2 = Bp[(b3 + 2) * 128 + 64 + lane];

        f32x4 acc[4];
#pragma unroll
        for (int mt = 0; mt < 4; ++mt)
#pragma unroll
            for (int r = 0; r < 4; ++r) acc[mt][r] = 0.f;

#pragma unroll
        for (int mt = 0; mt < 4; ++mt) {
            const unsigned short* ar = Acur + (mt * 16 + c) * KS;
            bf16x8 a0 = *(const bf16x8*)(ar + q * 8);
            bf16x8 a1 = *(const bf16x8*)(ar + 32 + q * 8);
            bf16x8 a2 = *(const bf16x8*)(ar + 64 + q * 8);
            acc[mt] = __builtin_amdgcn_mfma_f32_16x16x32_bf16(a0, bh0, acc[mt], 0, 0, 0);
            acc[mt] = __builtin_amdgcn_mfma_f32_16x16x32_bf16(a0, bl0, acc[mt], 0, 0, 0);
            acc[mt] = __builtin_amdgcn_mfma_f32_16x16x32_bf16(a1, bh1, acc[mt], 0, 0, 0);
            acc[mt] = __builtin_amdgcn_mfma_f32_16x16x32_bf16(a1, bl1, acc[mt], 0, 0, 0);
            acc[mt] = __builtin_amdgcn_mfma_f32_16x16x32_bf16(a2, bh2, acc[mt], 0, 0, 0);
            acc[mt] = __builtin_amdgcn_mfma_f32_16x16x32_bf16(a2, bl2, acc[mt], 0, 0, 0);
        }

        const bool scale = (tl < 3);
#pragma unroll
        for (int mt = 0; mt < 4; ++mt) {
#pragma unroll
            for (int r = 0; r < 4; ++r) {
                int m = mt * 16 + q * 4 + r;
                float v = fmaxf(acc[mt][r], 0.f);
                if (scale) v *= degs[m];
                Anxt[m * KS + hh] = f2bf(v);
            }
        }
        __syncthreads();
        unsigned short* tmp = Acur; Acur = Anxt; Anxt = tmp;
    }

    {
        bf16x8 bh0 = W7p[(w * 2 + 0) * 128 + lane], bl0 = W7p[(w * 2 + 0) * 128 + 64 + lane];
        bf16x8 bh1 = W7p[(w * 2 + 1) * 128 + lane], bl1 = W7p[(w * 2 + 1) * 128 + 64 + lane];
        f32x4 acc[4];
#pragma unroll
        for (int mt = 0; mt < 4; ++mt)
#pragma unroll
            for (int r = 0; r < 4; ++r) acc[mt][r] = 0.f;
#pragma unroll
        for (int mt = 0; mt < 4; ++mt) {
            const unsigned short* ar = Acur + (mt * 16 + c) * KS;
            bf16x8 a0 = *(const bf16x8*)(ar + q * 8);
            bf16x8 a1 = *(const bf16x8*)(ar + 32 + q * 8);
            acc[mt] = __builtin_amdgcn_mfma_f32_16x16x32_bf16(a0, bh0, acc[mt], 0, 0, 0);
            acc[mt] = __builtin_amdgcn_mfma_f32_16x16x32_bf16(a0, bl0, acc[mt], 0, 0, 0);
            acc[mt] = __builtin_amdgcn_mfma_f32_16x16x32_bf16(a1, bh1, acc[mt], 0, 0, 0);
            acc[mt] = __builtin_amdgcn_mfma_f32_16x16x32_bf16(a1, bl1, acc[mt], 0, 0, 0);
        }
        float w5v = W5[H + hh];
#pragma unroll
        for (int mt = 0; mt < 4; ++mt) {
#pragma unroll
            for (int r = 0; r < 4; ++r) {
                float v = fmaxf(acc[mt][r], 0.f) * w5v;
                v += __shfl_xor(v, 1);
                v += __shfl_xor(v, 2);
                v += __shfl_xor(v, 4);
                v += __shfl_xor(v, 8);
                if (c == 0) red[w * 64 + mt * 16 + q * 4 + r] = v;
            }
        }
    }
    __syncthreads();
    if (t < 64) {
        float pn = red[t] + red[64 + t] + red[128 + t] + red[192 + t];
        if (base + t < N) out[base + t] = pn;
    }
    __syncthreads();

    {
        int h = t & 63, mq = t >> 6;
        float s = 0.f;
#pragma unroll
        for (int i = 0; i < 16; ++i) s += bf2f(Acur[(mq * 16 + i) * KS + h]);
        red[t] = s;
    }
    __syncthreads();
    if (t < 64) {
        float g = red[t] + red[64 + t] + red[128 + t] + red[192 + t];
        unsafeAtomicAdd(&gp[t], g);
    }
}

__global__ __launch_bounds__(256)
void finalize_kernel(const float* __restrict__ gp, const float* __restrict__ W5,
                     float* __restrict__ out, int N) {
    int lane = threadIdx.x & 63;
    float v = fmaxf(gp[lane], 0.f) * W5[lane];
    v += __shfl_xor(v, 1);
    v += __shfl_xor(v, 2);
    v += __shfl_xor(v, 4);
    v += __shfl_xor(v, 8);
    v += __shfl_xor(v, 16);
    v += __shfl_xor(v, 32);
    int n = blockIdx.x * blockDim.x + threadIdx.x;
    if (n < N) out[n] += v;
}

// ---------------------------------------------------------------------------
extern "C" void kernel_launch(void* const* d_in, const int* in_sizes, int n_in,
                              void* d_out, int out_size, void* d_ws, size_t ws_size,
                              hipStream_t stream) {
    const float* mu = (const float*)d_in[0];
    const float* x  = (const float*)d_in[1];
    const int*   ei = (const int*)d_in[2];
    const float* ew = (const float*)d_in[3];
    const float* W1 = (const float*)d_in[4];
    const float* W2 = (const float*)d_in[5];
    const float* W3 = (const float*)d_in[6];
    const float* W4 = (const float*)d_in[7];
    const float* W5 = (const float*)d_in[8];
    const float* W7 = (const float*)d_in[9];
    float* out = (float*)d_out;

    const int N = in_sizes[1];
    const int E = in_sizes[3];

    char* ws = (char*)d_ws;
    double* dS  = (double*)ws;                                  // N*8
    float*  gp  = (float*)(ws + (size_t)N * 8);                 // 256 B
    bf16x8* Bp  = (bf16x8*)(ws + (size_t)N * 8 + 256);          // 196608 B
    bf16x8* W7p = (bf16x8*)(ws + (size_t)N * 8 + 256 + 196608); // 32768 B

    const int nT = (N + NPB - 1) / NPB;

    // one-time cooperative-capability probe (host-only queries; capture-safe)
    static int coop_state = -1;   // -1 unknown, 0 unusable, 1 usable
    static int cap_blocks = 0;
    if (coop_state == -1) {
        int dev = 0;
        (void)hipGetDevice(&dev);
        int attr = 0, cu = 0, nb = 0;
        (void)hipDeviceGetAttribute(&attr, hipDeviceAttributeCooperativeLaunch, dev);
        (void)hipDeviceGetAttribute(&cu, hipDeviceAttributeMultiprocessorCount, dev);
        hipError_t oe = hipOccupancyMaxActiveBlocksPerMultiprocessor(
            &nb, reinterpret_cast<const void*>(&fused_kernel), 256, 0);
        if (attr && oe == hipSuccess && nb > 0 && cu > 0) {
            coop_state = 1;
            cap_blocks = nb * cu;
        } else {
            coop_state = 0;
        }
    }

    bool launched = false;
    if (coop_state == 1) {
        int grid = nT < cap_blocks ? nT : cap_blocks;
        if (grid >= 20 && (long long)grid * 4 >= (long long)nT) {
            int N_ = N, E_ = E, nT_ = nT;
            void* args[] = {(void*)&mu, (void*)&x, (void*)&ei, (void*)&ew,
                            (void*)&W1, (void*)&W2, (void*)&W3, (void*)&W4,
                            (void*)&W5, (void*)&W7, (void*)&dS, (void*)&gp,
                            (void*)&Bp, (void*)&W7p, (void*)&out,
                            (void*)&N_, (void*)&E_, (void*)&nT_};
            hipError_t e = hipLaunchCooperativeKernel(
                reinterpret_cast<const void*>(&fused_kernel),
                dim3(grid), dim3(256), args, 0, stream);
            if (e == hipSuccess) {
                launched = true;
            } else {
                coop_state = 0;
                (void)hipGetLastError();
            }
        } else {
            coop_state = 0;
        }
    }

    if (!launched) {
        int zero_dwords = N * 2 + 64;
        prep_kernel<<<65, 256, 0, stream>>>(W1, W2, W3, W4, W7, (unsigned*)dS,
                                            zero_dwords, Bp, W7p);
        edge_kernel<<<(E + 1023) / 1024, 256, 0, stream>>>(ei, ew, dS, E);
        node_kernel<<<(N + NPB - 1) / NPB, 256, 0, stream>>>(mu, x, W5, Bp, W7p,
                                                             dS, gp, out, N);
        finalize_kernel<<<(N + 255) / 256, 256, 0, stream>>>(gp, W5, out, N);
    }
}

// Round 2
// 151.800 us; speedup vs baseline: 2.0727x; 2.0727x over previous
//
#include <hip/hip_runtime.h>

#define H 64
#define NPB 64
#define KS 104      // bf16 elems per A-row: 64 data + xv + sv + zero-pad; 208B = 13x16B
typedef short bf16x8 __attribute__((ext_vector_type(8)));
typedef float f32x4 __attribute__((ext_vector_type(4)));

static __device__ __forceinline__ unsigned short f2bf(float f) {
    union { float f; unsigned u; } v; v.f = f;
    unsigned r = v.u + 0x7fffu + ((v.u >> 16) & 1u);
    return (unsigned short)(r >> 16);
}
static __device__ __forceinline__ float bf2f(unsigned short b) {
    union { unsigned u; float f; } v; v.u = ((unsigned)b) << 16;
    return v.f;
}
static __device__ __forceinline__ void split8(const float* ff, bf16x8& hi, bf16x8& lo) {
#pragma unroll
    for (int j = 0; j < 8; ++j) {
        unsigned short h = f2bf(ff[j]);
        hi[j] = (short)h;
        lo[j] = (short)f2bf(ff[j] - bf2f(h));
    }
}

// ws layout (bytes): dS [N*8] | gp [256] | Bpre [196608] | W7pre [32768]
// Bpre frag index: ((tl*4+w)*3+s)*128 + hilo*64 + lane   (each entry = 8 bf16)
// W7pre frag index: (w*2+s)*128 + hilo*64 + lane

// ---------------------------------------------------------------------------
// Block 0: build pre-split weight fragments. Blocks 1..: zero dS+gp.
__global__ __launch_bounds__(256)
void prep_kernel(const float* __restrict__ W1, const float* __restrict__ W2,
                 const float* __restrict__ W3, const float* __restrict__ W4,
                 const float* __restrict__ W7, unsigned* __restrict__ zero_base,
                 int zero_dwords, bf16x8* __restrict__ Bp, bf16x8* __restrict__ W7p) {
    const int t = threadIdx.x;
    if (blockIdx.x != 0) {
        int idx = (blockIdx.x - 1) * 256 + t;
        for (int i = idx; i < zero_dwords; i += 64 * 256) zero_base[i] = 0u;
        return;
    }
    __shared__ float v3s[4 * H];
    {   // v3[tl][h] = sum_k relu(W4[tl][k]) * W3[tl][h][k]
        int tl = t >> 6, h = t & 63;
        const float* __restrict__ w3r = W3 + (tl * H + h) * H;
        const float* __restrict__ w4r = W4 + tl * H;
        float a0 = 0, a1 = 0, a2 = 0, a3 = 0;
#pragma unroll
        for (int k = 0; k < H; k += 4) {
            a0 += fmaxf(w4r[k + 0], 0.f) * w3r[k + 0];
            a1 += fmaxf(w4r[k + 1], 0.f) * w3r[k + 1];
            a2 += fmaxf(w4r[k + 2], 0.f) * w3r[k + 2];
            a3 += fmaxf(w4r[k + 3], 0.f) * w3r[k + 3];
        }
        v3s[t] = (a0 + a1) + (a2 + a3);
    }
    __syncthreads();
    const int w = t >> 6, lane = t & 63, c = lane & 15, q = lane >> 4;
    const int hh = 16 * w + c;
    for (int tl = 0; tl < 4; ++tl) {
        const int b3 = (tl * 4 + w) * 3;
        bf16x8 hi, lo;
#pragma unroll
        for (int s = 0; s < 2; ++s) {
            const float* __restrict__ wp = W2 + (tl * H + hh) * H + s * 32 + q * 8;
            float4 f0 = *(const float4*)(wp);
            float4 f1 = *(const float4*)(wp + 4);
            float ff[8] = {f0.x, f0.y, f0.z, f0.w, f1.x, f1.y, f1.z, f1.w};
            split8(ff, hi, lo);
            Bp[(b3 + s) * 128 + lane] = hi;
            Bp[(b3 + s) * 128 + 64 + lane] = lo;
        }
        float ff[8] = {0, 0, 0, 0, 0, 0, 0, 0};
        if (q == 0) { ff[0] = W1[tl * H + hh]; ff[1] = v3s[tl * H + hh]; }
        split8(ff, hi, lo);
        Bp[(b3 + 2) * 128 + lane] = hi;
        Bp[(b3 + 2) * 128 + 64 + lane] = lo;
    }
#pragma unroll
    for (int s = 0; s < 2; ++s) {
        const float* __restrict__ wp = W7 + hh * H + s * 32 + q * 8;
        float4 f0 = *(const float4*)(wp);
        float4 f1 = *(const float4*)(wp + 4);
        float ff[8] = {f0.x, f0.y, f0.z, f0.w, f1.x, f1.y, f1.z, f1.w};
        bf16x8 hi, lo;
        split8(ff, hi, lo);
        W7p[(w * 2 + s) * 128 + lane] = hi;
        W7p[(w * 2 + s) * 128 + 64 + lane] = lo;
    }
}

// ---------------------------------------------------------------------------
// 4 edges/thread; one fp64 atomic per edge packs deg & S: T = 4096*deg + S.
__global__ __launch_bounds__(256)
void edge_kernel(const int* __restrict__ ei, const float* __restrict__ ew,
                 double* __restrict__ dS, int E) {
    int probe = ei[2 * (threadIdx.x & 63) + 1];
    bool is64 = (__ballot(probe != 0) == 0ULL);           // wave-uniform
    int e0 = 4 * (blockIdx.x * blockDim.x + threadIdx.x);
    if (e0 >= E) return;
    if (e0 + 3 < E) {
        float4 wv = *(const float4*)(ew + e0);
        int i0, i1, i2, i3;
        if (is64) {
            int4 a = *(const int4*)(ei + 2 * (E + e0));
            int4 b = *(const int4*)(ei + 2 * (E + e0) + 4);
            i0 = a.x; i1 = a.z; i2 = b.x; i3 = b.z;
        } else {
            int4 a = *(const int4*)(ei + E + e0);
            i0 = a.x; i1 = a.y; i2 = a.z; i3 = a.w;
        }
        unsafeAtomicAdd(&dS[i0], 4096.0 + (double)wv.x);
        unsafeAtomicAdd(&dS[i1], 4096.0 + (double)wv.y);
        unsafeAtomicAdd(&dS[i2], 4096.0 + (double)wv.z);
        unsafeAtomicAdd(&dS[i3], 4096.0 + (double)wv.w);
    } else {
        for (int j = 0; j < 4 && e0 + j < E; ++j) {
            int e = e0 + j;
            int idx = is64 ? ei[2 * (E + e)] : ei[E + e];
            unsafeAtomicAdd(&dS[idx], 4096.0 + (double)ew[e]);
        }
    }
}

// ---------------------------------------------------------------------------
// 4 blocks/CU: LDS 28.2KB*4 = 112.6KB < 160KB, VGPR 68 <= 128. The kernel is
// latency-bound (barrier-separated stages, dependent MFMA chains) — occupancy
// is the lever, not pipe throughput.
__global__ __launch_bounds__(256, 4)
void node_kernel(const float* __restrict__ mu, const float* __restrict__ x,
                 const float* __restrict__ W5, const bf16x8* __restrict__ Bp,
                 const bf16x8* __restrict__ W7p, const double* __restrict__ dS,
                 float* __restrict__ gp, float* __restrict__ out, int N) {
    __shared__ unsigned short Ab[2][NPB * KS];
    __shared__ float degs[NPB];
    __shared__ float red[4 * NPB];

    const int t = threadIdx.x;
    const int lane = t & 63;
    const int w = __builtin_amdgcn_readfirstlane(t >> 6);
    const int c = lane & 15;
    const int q = lane >> 4;
    const int hh = 16 * w + c;
    const int base = blockIdx.x * NPB;

    // zero only pad cols 66..103 (dwords 33..51) of every row, both buffers
    if (t < 128) {
        int buf = t >> 6, row = t & 63;
        unsigned* p = (unsigned*)&Ab[buf][row * KS];
#pragma unroll
        for (int d = 33; d < 52; ++d) p[d] = 0u;
    }
    // per-node scalars; xv/sv -> cols 64/65 of BOTH buffers
    if (t < 64) {
        int node = base + t;
        float dg = 0.f, sv = 0.f, xv = 0.f;
        if (node < N) {
            double T = dS[node];
            double k = floor(T * (1.0 / 4096.0));
            dg = (float)k;
            sv = (float)(T - 4096.0 * k);
            xv = x[node];
        }
        degs[t] = dg;
        unsigned short xb = f2bf(xv), sb = f2bf(sv);
        Ab[0][t * KS + 64] = xb; Ab[0][t * KS + 65] = sb;
        Ab[1][t * KS + 64] = xb; Ab[1][t * KS + 65] = sb;
    }
    __syncthreads();

    // stage A0 = deg[m] * mu (bf16), coalesced
    {
        const float* __restrict__ mublk = mu + (size_t)base * H;
        const int maxf = (N - base) * H;
#pragma unroll
        for (int cc = 0; cc < 4; ++cc) {
            int f = (t + 256 * cc) * 4;
            float4 v = make_float4(0.f, 0.f, 0.f, 0.f);
            if (f < maxf) v = *(const float4*)(mublk + f);
            int m = f >> 6, k = f & 63;
            float dg = degs[m];
            ushort4 b;
            b.x = f2bf(v.x * dg); b.y = f2bf(v.y * dg);
            b.z = f2bf(v.z * dg); b.w = f2bf(v.w * dg);
            *(ushort4*)(&Ab[0][m * KS + k]) = b;
        }
    }
    __syncthreads();

    unsigned short* Acur = &Ab[0][0];
    unsigned short* Anxt = &Ab[1][0];

    for (int tl = 0; tl < 4; ++tl) {
        const int b3 = (tl * 4 + w) * 3;
        bf16x8 bh0 = Bp[(b3 + 0) * 128 + lane], bl0 = Bp[(b3 + 0) * 128 + 64 + lane];
        bf16x8 bh1 = Bp[(b3 + 1) * 128 + lane], bl1 = Bp[(b3 + 1) * 128 + 64 + lane];
        bf16x8 bh2 = Bp[(b3 + 2) * 128 + lane], bl2 = Bp[(b3 + 2) * 128 + 64 + lane];

        f32x4 acc[4];
#pragma unroll
        for (int mt = 0; mt < 4; ++mt)
#pragma unroll
            for (int r = 0; r < 4; ++r) acc[mt][r] = 0.f;

#pragma unroll
        for (int mt = 0; mt < 4; ++mt) {
            const unsigned short* ar = Acur + (mt * 16 + c) * KS;
            bf16x8 a0 = *(const bf16x8*)(ar + q * 8);
            bf16x8 a1 = *(const bf16x8*)(ar + 32 + q * 8);
            bf16x8 a2 = *(const bf16x8*)(ar + 64 + q * 8);
            acc[mt] = __builtin_amdgcn_mfma_f32_16x16x32_bf16(a0, bh0, acc[mt], 0, 0, 0);
            acc[mt] = __builtin_amdgcn_mfma_f32_16x16x32_bf16(a0, bl0, acc[mt], 0, 0, 0);
            acc[mt] = __builtin_amdgcn_mfma_f32_16x16x32_bf16(a1, bh1, acc[mt], 0, 0, 0);
            acc[mt] = __builtin_amdgcn_mfma_f32_16x16x32_bf16(a1, bl1, acc[mt], 0, 0, 0);
            acc[mt] = __builtin_amdgcn_mfma_f32_16x16x32_bf16(a2, bh2, acc[mt], 0, 0, 0);
            acc[mt] = __builtin_amdgcn_mfma_f32_16x16x32_bf16(a2, bl2, acc[mt], 0, 0, 0);
        }

        const bool scale = (tl < 3);
#pragma unroll
        for (int mt = 0; mt < 4; ++mt) {
#pragma unroll
            for (int r = 0; r < 4; ++r) {
                int m = mt * 16 + q * 4 + r;
                float v = fmaxf(acc[mt][r], 0.f);
                if (scale) v *= degs[m];
                Anxt[m * KS + hh] = f2bf(v);
            }
        }
        __syncthreads();
        unsigned short* tmp = Acur; Acur = Anxt; Anxt = tmp;
    }

    // W7 matmul + per-node term: pn[m] = sum_h relu(mu.W7[h,:]) * W5[64+h]
    {
        bf16x8 bh0 = W7p[(w * 2 + 0) * 128 + lane], bl0 = W7p[(w * 2 + 0) * 128 + 64 + lane];
        bf16x8 bh1 = W7p[(w * 2 + 1) * 128 + lane], bl1 = W7p[(w * 2 + 1) * 128 + 64 + lane];
        f32x4 acc[4];
#pragma unroll
        for (int mt = 0; mt < 4; ++mt)
#pragma unroll
            for (int r = 0; r < 4; ++r) acc[mt][r] = 0.f;
#pragma unroll
        for (int mt = 0; mt < 4; ++mt) {
            const unsigned short* ar = Acur + (mt * 16 + c) * KS;
            bf16x8 a0 = *(const bf16x8*)(ar + q * 8);
            bf16x8 a1 = *(const bf16x8*)(ar + 32 + q * 8);
            acc[mt] = __builtin_amdgcn_mfma_f32_16x16x32_bf16(a0, bh0, acc[mt], 0, 0, 0);
            acc[mt] = __builtin_amdgcn_mfma_f32_16x16x32_bf16(a0, bl0, acc[mt], 0, 0, 0);
            acc[mt] = __builtin_amdgcn_mfma_f32_16x16x32_bf16(a1, bh1, acc[mt], 0, 0, 0);
            acc[mt] = __builtin_amdgcn_mfma_f32_16x16x32_bf16(a1, bl1, acc[mt], 0, 0, 0);
        }
        float w5v = W5[H + hh];
#pragma unroll
        for (int mt = 0; mt < 4; ++mt) {
#pragma unroll
            for (int r = 0; r < 4; ++r) {
                float v = fmaxf(acc[mt][r], 0.f) * w5v;
                v += __shfl_xor(v, 1);
                v += __shfl_xor(v, 2);
                v += __shfl_xor(v, 4);
                v += __shfl_xor(v, 8);
                if (c == 0) red[w * 64 + mt * 16 + q * 4 + r] = v;
            }
        }
    }
    __syncthreads();
    if (t < 64) {
        float pn = red[t] + red[64 + t] + red[128 + t] + red[192 + t];
        if (base + t < N) out[base + t] = pn;
    }
    __syncthreads();

    // graph pool partials from final mu
    {
        int h = t & 63, mq = t >> 6;
        float s = 0.f;
#pragma unroll
        for (int i = 0; i < 16; ++i) s += bf2f(Acur[(mq * 16 + i) * KS + h]);
        red[t] = s;
    }
    __syncthreads();
    if (t < 64) {
        float g = red[t] + red[64 + t] + red[128 + t] + red[192 + t];
        unsafeAtomicAdd(&gp[t], g);
    }
}

// ---------------------------------------------------------------------------
// out[n] += C, C = sum_h relu(gp[h])*W5[h]; one gp read + wave reduce per wave.
__global__ __launch_bounds__(256)
void finalize_kernel(const float* __restrict__ gp, const float* __restrict__ W5,
                     float* __restrict__ out, int N) {
    int lane = threadIdx.x & 63;
    float v = fmaxf(gp[lane], 0.f) * W5[lane];
    v += __shfl_xor(v, 1);
    v += __shfl_xor(v, 2);
    v += __shfl_xor(v, 4);
    v += __shfl_xor(v, 8);
    v += __shfl_xor(v, 16);
    v += __shfl_xor(v, 32);
    int n = blockIdx.x * blockDim.x + threadIdx.x;
    if (n < N) out[n] += v;
}

// ---------------------------------------------------------------------------
extern "C" void kernel_launch(void* const* d_in, const int* in_sizes, int n_in,
                              void* d_out, int out_size, void* d_ws, size_t ws_size,
                              hipStream_t stream) {
    const float* mu = (const float*)d_in[0];
    const float* x  = (const float*)d_in[1];
    const int*   ei = (const int*)d_in[2];
    const float* ew = (const float*)d_in[3];
    const float* W1 = (const float*)d_in[4];
    const float* W2 = (const float*)d_in[5];
    const float* W3 = (const float*)d_in[6];
    const float* W4 = (const float*)d_in[7];
    const float* W5 = (const float*)d_in[8];
    const float* W7 = (const float*)d_in[9];
    float* out = (float*)d_out;

    const int N = in_sizes[1];
    const int E = in_sizes[3];

    char* ws = (char*)d_ws;
    double* dS  = (double*)ws;                                  // N*8
    float*  gp  = (float*)(ws + (size_t)N * 8);                 // 256 B
    bf16x8* Bp  = (bf16x8*)(ws + (size_t)N * 8 + 256);          // 196608 B
    bf16x8* W7p = (bf16x8*)(ws + (size_t)N * 8 + 256 + 196608); // 32768 B
    int zero_dwords = N * 2 + 64;

    prep_kernel<<<65, 256, 0, stream>>>(W1, W2, W3, W4, W7, (unsigned*)dS,
                                        zero_dwords, Bp, W7p);
    edge_kernel<<<(E + 1023) / 1024, 256, 0, stream>>>(ei, ew, dS, E);
    node_kernel<<<(N + NPB - 1) / NPB, 256, 0, stream>>>(mu, x, W5, Bp, W7p,
                                                         dS, gp, out, N);
    finalize_kernel<<<(N + 255) / 256, 256, 0, stream>>>(gp, W5, out, N);
}

// Round 3
// 146.125 us; speedup vs baseline: 2.1532x; 1.0388x over previous
//
#include <hip/hip_runtime.h>

#define H 64
#define NPB 64
#define KS 104      // bf16 elems per A-row: 64 data + xv + sv + zero-pad; 208B = 13x16B
typedef short bf16x8 __attribute__((ext_vector_type(8)));
typedef float f32x4 __attribute__((ext_vector_type(4)));

static __device__ __forceinline__ unsigned short f2bf(float f) {
    union { float f; unsigned u; } v; v.f = f;
    unsigned r = v.u + 0x7fffu + ((v.u >> 16) & 1u);
    return (unsigned short)(r >> 16);
}
static __device__ __forceinline__ float bf2f(unsigned short b) {
    union { unsigned u; float f; } v; v.u = ((unsigned)b) << 16;
    return v.f;
}
static __device__ __forceinline__ void split8(const float* ff, bf16x8& hi, bf16x8& lo) {
#pragma unroll
    for (int j = 0; j < 8; ++j) {
        unsigned short h = f2bf(ff[j]);
        hi[j] = (short)h;
        lo[j] = (short)f2bf(ff[j] - bf2f(h));
    }
}

// ws layout (bytes): dS [N*8] | gp [256] | Bpre [196608] | W7pre [32768]
// Bpre frag index: ((tl*4+w)*3+s)*128 + hilo*64 + lane   (each entry = 8 bf16)
// W7pre frag index: (w*2+s)*128 + hilo*64 + lane

// ---------------------------------------------------------------------------
// Block 0: build pre-split weight fragments. Blocks 1..: zero dS+gp.
__global__ __launch_bounds__(256)
void prep_kernel(const float* __restrict__ W1, const float* __restrict__ W2,
                 const float* __restrict__ W3, const float* __restrict__ W4,
                 const float* __restrict__ W7, unsigned* __restrict__ zero_base,
                 int zero_dwords, bf16x8* __restrict__ Bp, bf16x8* __restrict__ W7p) {
    const int t = threadIdx.x;
    if (blockIdx.x != 0) {
        int idx = (blockIdx.x - 1) * 256 + t;
        for (int i = idx; i < zero_dwords; i += 64 * 256) zero_base[i] = 0u;
        return;
    }
    __shared__ float v3s[4 * H];
    {   // v3[tl][h] = sum_k relu(W4[tl][k]) * W3[tl][h][k]
        int tl = t >> 6, h = t & 63;
        const float* __restrict__ w3r = W3 + (tl * H + h) * H;
        const float* __restrict__ w4r = W4 + tl * H;
        float a0 = 0, a1 = 0, a2 = 0, a3 = 0;
#pragma unroll
        for (int k = 0; k < H; k += 4) {
            a0 += fmaxf(w4r[k + 0], 0.f) * w3r[k + 0];
            a1 += fmaxf(w4r[k + 1], 0.f) * w3r[k + 1];
            a2 += fmaxf(w4r[k + 2], 0.f) * w3r[k + 2];
            a3 += fmaxf(w4r[k + 3], 0.f) * w3r[k + 3];
        }
        v3s[t] = (a0 + a1) + (a2 + a3);
    }
    __syncthreads();
    const int w = t >> 6, lane = t & 63, c = lane & 15, q = lane >> 4;
    const int hh = 16 * w + c;
    for (int tl = 0; tl < 4; ++tl) {
        const int b3 = (tl * 4 + w) * 3;
        bf16x8 hi, lo;
#pragma unroll
        for (int s = 0; s < 2; ++s) {
            const float* __restrict__ wp = W2 + (tl * H + hh) * H + s * 32 + q * 8;
            float4 f0 = *(const float4*)(wp);
            float4 f1 = *(const float4*)(wp + 4);
            float ff[8] = {f0.x, f0.y, f0.z, f0.w, f1.x, f1.y, f1.z, f1.w};
            split8(ff, hi, lo);
            Bp[(b3 + s) * 128 + lane] = hi;
            Bp[(b3 + s) * 128 + 64 + lane] = lo;
        }
        float ff[8] = {0, 0, 0, 0, 0, 0, 0, 0};
        if (q == 0) { ff[0] = W1[tl * H + hh]; ff[1] = v3s[tl * H + hh]; }
        split8(ff, hi, lo);
        Bp[(b3 + 2) * 128 + lane] = hi;
        Bp[(b3 + 2) * 128 + 64 + lane] = lo;
    }
#pragma unroll
    for (int s = 0; s < 2; ++s) {
        const float* __restrict__ wp = W7 + hh * H + s * 32 + q * 8;
        float4 f0 = *(const float4*)(wp);
        float4 f1 = *(const float4*)(wp + 4);
        float ff[8] = {f0.x, f0.y, f0.z, f0.w, f1.x, f1.y, f1.z, f1.w};
        bf16x8 hi, lo;
        split8(ff, hi, lo);
        W7p[(w * 2 + s) * 128 + lane] = hi;
        W7p[(w * 2 + s) * 128 + 64 + lane] = lo;
    }
}

// ---------------------------------------------------------------------------
// 8 edges/thread; one fp64 atomic per edge packs deg & S: T = 4096*deg + S.
__global__ __launch_bounds__(256)
void edge_kernel(const int* __restrict__ ei, const float* __restrict__ ew,
                 double* __restrict__ dS, int E) {
    int probe = ei[2 * (threadIdx.x & 63) + 1];
    bool is64 = (__ballot(probe != 0) == 0ULL);           // wave-uniform
    int e0 = 8 * (blockIdx.x * blockDim.x + threadIdx.x);
    if (e0 >= E) return;
    if (e0 + 7 < E) {
        float4 w0 = *(const float4*)(ew + e0);
        float4 w1 = *(const float4*)(ew + e0 + 4);
        int i0, i1, i2, i3, i4, i5, i6, i7;
        if (is64) {
            int4 a = *(const int4*)(ei + 2 * (E + e0));
            int4 b = *(const int4*)(ei + 2 * (E + e0) + 4);
            int4 cc = *(const int4*)(ei + 2 * (E + e0) + 8);
            int4 d = *(const int4*)(ei + 2 * (E + e0) + 12);
            i0 = a.x; i1 = a.z; i2 = b.x; i3 = b.z;
            i4 = cc.x; i5 = cc.z; i6 = d.x; i7 = d.z;
        } else {
            int4 a = *(const int4*)(ei + E + e0);
            int4 b = *(const int4*)(ei + E + e0 + 4);
            i0 = a.x; i1 = a.y; i2 = a.z; i3 = a.w;
            i4 = b.x; i5 = b.y; i6 = b.z; i7 = b.w;
        }
        unsafeAtomicAdd(&dS[i0], 4096.0 + (double)w0.x);
        unsafeAtomicAdd(&dS[i1], 4096.0 + (double)w0.y);
        unsafeAtomicAdd(&dS[i2], 4096.0 + (double)w0.z);
        unsafeAtomicAdd(&dS[i3], 4096.0 + (double)w0.w);
        unsafeAtomicAdd(&dS[i4], 4096.0 + (double)w1.x);
        unsafeAtomicAdd(&dS[i5], 4096.0 + (double)w1.y);
        unsafeAtomicAdd(&dS[i6], 4096.0 + (double)w1.z);
        unsafeAtomicAdd(&dS[i7], 4096.0 + (double)w1.w);
    } else {
        for (int j = 0; j < 8 && e0 + j < E; ++j) {
            int e = e0 + j;
            int idx = is64 ? ei[2 * (E + e)] : ei[E + e];
            unsafeAtomicAdd(&dS[idx], 4096.0 + (double)ew[e]);
        }
    }
}

// ---------------------------------------------------------------------------
// 4 blocks/CU. Weight fragments are software-pipelined: layer-0 frags load
// before the staging barrier; layer t+1 (and W7 during the last layer) load
// while layer t's MFMAs run — no global-load dependency inside any stage.
__global__ __launch_bounds__(256, 4)
void node_kernel(const float* __restrict__ mu, const float* __restrict__ x,
                 const float* __restrict__ W5, const bf16x8* __restrict__ Bp,
                 const bf16x8* __restrict__ W7p, const double* __restrict__ dS,
                 float* __restrict__ gp, float* __restrict__ out, int N) {
    __shared__ unsigned short Ab[2][NPB * KS];
    __shared__ float degs[NPB];
    __shared__ float red[4 * NPB];

    const int t = threadIdx.x;
    const int lane = t & 63;
    const int w = __builtin_amdgcn_readfirstlane(t >> 6);
    const int c = lane & 15;
    const int q = lane >> 4;
    const int hh = 16 * w + c;
    const int base = blockIdx.x * NPB;

    // prefetch layer-0 fragments (overlaps scalar phase + mu staging)
    bf16x8 fr[2][6];
    {
        const int b3 = w * 3;
        fr[0][0] = Bp[(b3 + 0) * 128 + lane]; fr[0][1] = Bp[(b3 + 0) * 128 + 64 + lane];
        fr[0][2] = Bp[(b3 + 1) * 128 + lane]; fr[0][3] = Bp[(b3 + 1) * 128 + 64 + lane];
        fr[0][4] = Bp[(b3 + 2) * 128 + lane]; fr[0][5] = Bp[(b3 + 2) * 128 + 64 + lane];
    }
    bf16x8 w7f[4];

    // zero only pad cols 66..103 (dwords 33..51) of every row, both buffers
    if (t < 128) {
        int buf = t >> 6, row = t & 63;
        unsigned* p = (unsigned*)&Ab[buf][row * KS];
#pragma unroll
        for (int d = 33; d < 52; ++d) p[d] = 0u;
    }
    // per-node scalars; xv/sv -> cols 64/65 of BOTH buffers
    if (t < 64) {
        int node = base + t;
        float dg = 0.f, sv = 0.f, xv = 0.f;
        if (node < N) {
            double T = dS[node];
            double k = floor(T * (1.0 / 4096.0));
            dg = (float)k;
            sv = (float)(T - 4096.0 * k);
            xv = x[node];
        }
        degs[t] = dg;
        unsigned short xb = f2bf(xv), sb = f2bf(sv);
        Ab[0][t * KS + 64] = xb; Ab[0][t * KS + 65] = sb;
        Ab[1][t * KS + 64] = xb; Ab[1][t * KS + 65] = sb;
    }
    __syncthreads();

    // stage A0 = deg[m] * mu (bf16), coalesced
    {
        const float* __restrict__ mublk = mu + (size_t)base * H;
        const int maxf = (N - base) * H;
#pragma unroll
        for (int cc = 0; cc < 4; ++cc) {
            int f = (t + 256 * cc) * 4;
            float4 v = make_float4(0.f, 0.f, 0.f, 0.f);
            if (f < maxf) v = *(const float4*)(mublk + f);
            int m = f >> 6, k = f & 63;
            float dg = degs[m];
            ushort4 b;
            b.x = f2bf(v.x * dg); b.y = f2bf(v.y * dg);
            b.z = f2bf(v.z * dg); b.w = f2bf(v.w * dg);
            *(ushort4*)(&Ab[0][m * KS + k]) = b;
        }
    }
    __syncthreads();

    unsigned short* Acur = &Ab[0][0];
    unsigned short* Anxt = &Ab[1][0];

#pragma unroll
    for (int tl = 0; tl < 4; ++tl) {
        const int cur = tl & 1, nxt = cur ^ 1;
        // prefetch next layer's fragments (or W7 frags during the last layer)
        if (tl < 3) {
            const int b3n = ((tl + 1) * 4 + w) * 3;
            fr[nxt][0] = Bp[(b3n + 0) * 128 + lane]; fr[nxt][1] = Bp[(b3n + 0) * 128 + 64 + lane];
            fr[nxt][2] = Bp[(b3n + 1) * 128 + lane]; fr[nxt][3] = Bp[(b3n + 1) * 128 + 64 + lane];
            fr[nxt][4] = Bp[(b3n + 2) * 128 + lane]; fr[nxt][5] = Bp[(b3n + 2) * 128 + 64 + lane];
        } else {
            w7f[0] = W7p[(w * 2 + 0) * 128 + lane]; w7f[1] = W7p[(w * 2 + 0) * 128 + 64 + lane];
            w7f[2] = W7p[(w * 2 + 1) * 128 + lane]; w7f[3] = W7p[(w * 2 + 1) * 128 + 64 + lane];
        }

        f32x4 acc[4];
#pragma unroll
        for (int mt = 0; mt < 4; ++mt)
#pragma unroll
            for (int r = 0; r < 4; ++r) acc[mt][r] = 0.f;

#pragma unroll
        for (int mt = 0; mt < 4; ++mt) {
            const unsigned short* ar = Acur + (mt * 16 + c) * KS;
            bf16x8 a0 = *(const bf16x8*)(ar + q * 8);
            bf16x8 a1 = *(const bf16x8*)(ar + 32 + q * 8);
            bf16x8 a2 = *(const bf16x8*)(ar + 64 + q * 8);
            acc[mt] = __builtin_amdgcn_mfma_f32_16x16x32_bf16(a0, fr[cur][0], acc[mt], 0, 0, 0);
            acc[mt] = __builtin_amdgcn_mfma_f32_16x16x32_bf16(a0, fr[cur][1], acc[mt], 0, 0, 0);
            acc[mt] = __builtin_amdgcn_mfma_f32_16x16x32_bf16(a1, fr[cur][2], acc[mt], 0, 0, 0);
            acc[mt] = __builtin_amdgcn_mfma_f32_16x16x32_bf16(a1, fr[cur][3], acc[mt], 0, 0, 0);
            acc[mt] = __builtin_amdgcn_mfma_f32_16x16x32_bf16(a2, fr[cur][4], acc[mt], 0, 0, 0);
            acc[mt] = __builtin_amdgcn_mfma_f32_16x16x32_bf16(a2, fr[cur][5], acc[mt], 0, 0, 0);
        }

        const bool scale = (tl < 3);
#pragma unroll
        for (int mt = 0; mt < 4; ++mt) {
#pragma unroll
            for (int r = 0; r < 4; ++r) {
                int m = mt * 16 + q * 4 + r;
                float v = fmaxf(acc[mt][r], 0.f);
                if (scale) v *= degs[m];
                Anxt[m * KS + hh] = f2bf(v);
            }
        }
        __syncthreads();
        unsigned short* tmp = Acur; Acur = Anxt; Anxt = tmp;
    }

    // W7 matmul + per-node term: pn[m] = sum_h relu(mu.W7[h,:]) * W5[64+h]
    {
        f32x4 acc[4];
#pragma unroll
        for (int mt = 0; mt < 4; ++mt)
#pragma unroll
            for (int r = 0; r < 4; ++r) acc[mt][r] = 0.f;
#pragma unroll
        for (int mt = 0; mt < 4; ++mt) {
            const unsigned short* ar = Acur + (mt * 16 + c) * KS;
            bf16x8 a0 = *(const bf16x8*)(ar + q * 8);
            bf16x8 a1 = *(const bf16x8*)(ar + 32 + q * 8);
            acc[mt] = __builtin_amdgcn_mfma_f32_16x16x32_bf16(a0, w7f[0], acc[mt], 0, 0, 0);
            acc[mt] = __builtin_amdgcn_mfma_f32_16x16x32_bf16(a0, w7f[1], acc[mt], 0, 0, 0);
            acc[mt] = __builtin_amdgcn_mfma_f32_16x16x32_bf16(a1, w7f[2], acc[mt], 0, 0, 0);
            acc[mt] = __builtin_amdgcn_mfma_f32_16x16x32_bf16(a1, w7f[3], acc[mt], 0, 0, 0);
        }
        float w5v = W5[H + hh];
#pragma unroll
        for (int mt = 0; mt < 4; ++mt) {
#pragma unroll
            for (int r = 0; r < 4; ++r) {
                float v = fmaxf(acc[mt][r], 0.f) * w5v;
                v += __shfl_xor(v, 1);
                v += __shfl_xor(v, 2);
                v += __shfl_xor(v, 4);
                v += __shfl_xor(v, 8);
                if (c == 0) red[w * 64 + mt * 16 + q * 4 + r] = v;
            }
        }
    }
    __syncthreads();
    if (t < 64) {
        float pn = red[t] + red[64 + t] + red[128 + t] + red[192 + t];
        if (base + t < N) out[base + t] = pn;
    }
    __syncthreads();

    // graph pool partials from final mu
    {
        int h = t & 63, mq = t >> 6;
        float s = 0.f;
#pragma unroll
        for (int i = 0; i < 16; ++i) s += bf2f(Acur[(mq * 16 + i) * KS + h]);
        red[t] = s;
    }
    __syncthreads();
    if (t < 64) {
        float g = red[t] + red[64 + t] + red[128 + t] + red[192 + t];
        unsafeAtomicAdd(&gp[t], g);
    }
}

// ---------------------------------------------------------------------------
// out[n] += C, C = sum_h relu(gp[h])*W5[h]; one gp read + wave reduce per wave.
__global__ __launch_bounds__(256)
void finalize_kernel(const float* __restrict__ gp, const float* __restrict__ W5,
                     float* __restrict__ out, int N) {
    int lane = threadIdx.x & 63;
    float v = fmaxf(gp[lane], 0.f) * W5[lane];
    v += __shfl_xor(v, 1);
    v += __shfl_xor(v, 2);
    v += __shfl_xor(v, 4);
    v += __shfl_xor(v, 8);
    v += __shfl_xor(v, 16);
    v += __shfl_xor(v, 32);
    int n = blockIdx.x * blockDim.x + threadIdx.x;
    if (n < N) out[n] += v;
}

// ---------------------------------------------------------------------------
extern "C" void kernel_launch(void* const* d_in, const int* in_sizes, int n_in,
                              void* d_out, int out_size, void* d_ws, size_t ws_size,
                              hipStream_t stream) {
    const float* mu = (const float*)d_in[0];
    const float* x  = (const float*)d_in[1];
    const int*   ei = (const int*)d_in[2];
    const float* ew = (const float*)d_in[3];
    const float* W1 = (const float*)d_in[4];
    const float* W2 = (const float*)d_in[5];
    const float* W3 = (const float*)d_in[6];
    const float* W4 = (const float*)d_in[7];
    const float* W5 = (const float*)d_in[8];
    const float* W7 = (const float*)d_in[9];
    float* out = (float*)d_out;

    const int N = in_sizes[1];
    const int E = in_sizes[3];

    char* ws = (char*)d_ws;
    double* dS  = (double*)ws;                                  // N*8
    float*  gp  = (float*)(ws + (size_t)N * 8);                 // 256 B
    bf16x8* Bp  = (bf16x8*)(ws + (size_t)N * 8 + 256);          // 196608 B
    bf16x8* W7p = (bf16x8*)(ws + (size_t)N * 8 + 256 + 196608); // 32768 B
    int zero_dwords = N * 2 + 64;

    prep_kernel<<<65, 256, 0, stream>>>(W1, W2, W3, W4, W7, (unsigned*)dS,
                                        zero_dwords, Bp, W7p);
    edge_kernel<<<(E + 2047) / 2048, 256, 0, stream>>>(ei, ew, dS, E);
    node_kernel<<<(N + NPB - 1) / NPB, 256, 0, stream>>>(mu, x, W5, Bp, W7p,
                                                         dS, gp, out, N);
    finalize_kernel<<<(N + 255) / 256, 256, 0, stream>>>(gp, W5, out, N);
}